// Round 3
// baseline (274.378 us; speedup 1.0000x reference)
//
#include <hip/hip_runtime.h>

#define SQRT5F 2.2360679774997896f

// out[i,a,j,b] = c^2 * ( (a==b) * A(i,j) * inv_l2[a]  -  5*fr(i,j)*D[i,j,a]*D[i,j,b] )
// with D[i,j,k] = (X1[i,k]-X2[j,k]) * inv_l2[k]
//      r^2      = sum_k (X1[i,k]-X2[j,k])^2 * inv_l2[k]
//      fr       = (5/3) * exp(-sqrt5 * r)
//      A        = fr * (1 + sqrt5 * r)
//
// v4: SEQUENTIAL per-wave store streams.
// History: v1 (2 threads/pair, 8 stores at 32KB stride/wave) = 2.8-3.0 TB/s
// writes vs fill's 6.5 TB/s. v2 (2j/thread + NT) regressed. v3 (persistent
// blocks, 32 stores/wave, hoisted prologue) = NEUTRAL -> issue continuity
// is not the limiter. Remaining delta vs fill: address ORDER. v1/v3 waves
// wrote 1KiB then jumped 32KB (a-stride) -> ~256B per DRAM channel per
// visit -> row-buffer thrash. v4 transposes the mapping: block=512thr=8
// waves <-> i, wave w <-> a-slab, wave sweeps j 0..m-1 in 32-j steps.
// Each step: lane t stores dense 16B at offset t*16 (1 KiB/instr, same as
// before), steps advance +1KiB -> each wave writes ONE pure 32KB
// sequential stream, fill's exact pattern.
// Per-(i,j) math recomputed per-a (8x): ~60 VALU x 2cy = 120cy per 1KiB
// vs 386 SIMD-cycles of BW-time per 1KiB at 6.5TB/s -> ~30% VALU, safe.
// All runtime-a indexing done via selector-fma / cndmask (no scratch).

__global__ __launch_bounds__(512) void deriv2_matern52_kernel(
    const float* __restrict__ X1,
    const float* __restrict__ X2,
    const float* __restrict__ c_ptr,
    const float* __restrict__ l_ptr,
    float* __restrict__ out,
    int m /* = 1024, multiple of 32 */)
{
    const int t    = threadIdx.x;
    const int w    = t >> 6;        // wave id == a (0..7)
    const int lane = t & 63;
    const int p    = lane >> 1;     // j-offset within a 32-j step group
    const int h    = lane & 1;      // which half of the 8-float b-run
    const int b0   = h << 2;        // 0 or 4

    const int i = blockIdx.x;

    const float c  = c_ptr[0];
    const float c2 = c * c;

    // lengthscales -> 1/l^2 (wave-uniform, loop-invariant)
    float inv_l2[8];
#pragma unroll
    for (int k = 0; k < 8; ++k) {
        const float lv = l_ptr[k];
        inv_l2[k] = 1.0f / (lv * lv);
    }

    // wave-uniform selectors for a == w (avoids runtime array indexing)
    float asel[8];
#pragma unroll
    for (int a = 0; a < 8; ++a) asel[a] = (a == w) ? 1.0f : 0.0f;

    // inv_l2[w] via selector reduction (loop-invariant)
    float il_w = 0.0f;
#pragma unroll
    for (int a = 0; a < 8; ++a) il_w = fmaf(asel[a], inv_l2[a], il_w);

    // diagonal hits this lane's quad iff (w>>2)==h, at element (w&3)
    float dk[4];
#pragma unroll
    for (int k = 0; k < 4; ++k)
        dk[k] = (((w & 3) == k) && ((w >> 2) == h)) ? 1.0f : 0.0f;

    // X1 row (32B wave-uniform broadcast, loop-invariant)
    const float4 x1a = ((const float4*)(X1 + (size_t)i * 8))[0];
    const float4 x1b = ((const float4*)(X1 + (size_t)i * 8))[1];
    const float x1v[8] = { x1a.x, x1a.y, x1a.z, x1a.w,
                           x1b.x, x1b.y, x1b.z, x1b.w };

    // out base for (i, a=w, j=p, b=b0); advances +1KiB (256 floats) per step
    float* op = out + (size_t)i * (size_t)(8 * m * 8)
                    + (size_t)w * (size_t)(m * 8)
                    + (size_t)p * 8 + b0;
    const float* xp = X2 + (size_t)p * 8;

    for (int s = 0; s < m; s += 32) {
        // X2 row for j = s + p (32KB total -> L1-resident after first sweep)
        const float4 x2a = ((const float4*)xp)[0];
        const float4 x2b = ((const float4*)xp)[1];
        const float x2v[8] = { x2a.x, x2a.y, x2a.z, x2a.w,
                               x2b.x, x2b.y, x2b.z, x2b.w };

        float D[8];
        float r2 = 0.0f;
#pragma unroll
        for (int k = 0; k < 8; ++k) {
            const float dx = x1v[k] - x2v[k];
            D[k] = dx * inv_l2[k];
            r2 += dx * D[k];                 // dx^2 * inv_l2
        }

        const float r  = sqrtf(r2);
        const float fr = (5.0f / 3.0f) * expf(-SQRT5F * r);
        const float A  = fr * (1.0f + SQRT5F * r);

        const float Acil = A * c2 * il_w;    // diagonal term value
        const float cf   = -5.0f * fr * c2;  // pair coefficient

        // D[w] via selector reduction (w wave-uniform; no runtime index)
        float Dw = 0.0f;
#pragma unroll
        for (int a = 0; a < 8; ++a) Dw = fmaf(asel[a], D[a], Dw);
        const float Dca = cf * Dw;

        // this lane's 4 b-values (h-select -> cndmask)
        const float Db[4] = { D[b0 + 0], D[b0 + 1], D[b0 + 2], D[b0 + 3] };

        float v[4];
#pragma unroll
        for (int k = 0; k < 4; ++k)
            v[k] = fmaf(dk[k], Acil, Dca * Db[k]);

        // lane t -> byte offset t*16 within the step's 1KiB: dense + aligned
        *(float4*)op = make_float4(v[0], v[1], v[2], v[3]);

        op += 32 * 8;                        // +1 KiB: pure sequential stream
        xp += 32 * 8;
    }
}

extern "C" void kernel_launch(void* const* d_in, const int* in_sizes, int n_in,
                              void* d_out, int out_size, void* d_ws, size_t ws_size,
                              hipStream_t stream) {
    const float* X1 = (const float*)d_in[0];
    const float* X2 = (const float*)d_in[1];
    const float* c  = (const float*)d_in[2];
    const float* l  = (const float*)d_in[3];
    float* out = (float*)d_out;

    const int d = in_sizes[3];        // 8
    const int n = in_sizes[0] / d;    // 1024
    const int m = in_sizes[1] / d;    // 1024

    dim3 grid(n);                     // one block per i
    dim3 block(512);                  // 8 waves: wave w owns a-slab w
    deriv2_matern52_kernel<<<grid, block, 0, stream>>>(X1, X2, c, l, out, m);
}

// Round 4
// 269.788 us; speedup vs baseline: 1.0170x; 1.0170x over previous
//
#include <hip/hip_runtime.h>

#define SQRT5F 2.2360679774997896f

// out[i,a,j,b] = c^2 * ( (a==b) * A(i,j) * inv_l2[a]  -  5*fr(i,j)*D[i,j,a]*D[i,j,b] )
// with D[i,j,k] = (X1[i,k]-X2[j,k]) * inv_l2[k]
//      r^2      = sum_k (X1[i,k]-X2[j,k])^2 * inv_l2[k]
//      fr       = (5/3) * exp(-sqrt5 * r)
//      A        = fr * (1 + sqrt5 * r)
//
// v5: BLOCK = CONTIGUOUS 32KB OUTPUT CHUNK, blocks in address order.
// Evidence ladder: fill (one compact marching device front) = 6.5 TB/s;
// v1/v3 (per-block 8x4KB chunks strided 32KB) = 2.9 TB/s; v4 (8192
// device-scattered per-wave streams) = 2.4 TB/s. Per-wave issue
// continuity (v3) and per-wave ordering (v4) are falsified; the
// remaining discriminator is DEVICE-WIDE footprint compactness (DRAM
// row/page locality per pseudo-channel). v5 maps block bid -> (i,a) =
// (bid>>3, bid&7), writing exactly out[bid*8192 .. +8192) floats: 32KB
// contiguous, 4KB per iteration, blocks in linear address order so the
// resident set forms a compact window marching through the output.
// Per-(i,j) math recomputed per-a (8x): ~55 VALU x 2cy per 1KiB store
// vs ~386 SIMD-cy of fair-share BW time -> ~30% VALU issue, safe.
// Runtime-a handled by hoisted selector fmas (no runtime reg indexing).

__global__ __launch_bounds__(256) void deriv2_matern52_kernel(
    const float* __restrict__ X1,
    const float* __restrict__ X2,
    const float* __restrict__ c_ptr,
    const float* __restrict__ l_ptr,
    float* __restrict__ out,
    int m /* = 1024, multiple of 128 */)
{
    const int t  = threadIdx.x;
    const int h  = t & 1;           // which half of the 8-float b-run
    const int p  = t >> 1;          // j-offset within a 128-j step (0..127)

    const int bid = blockIdx.x;
    const int a   = bid & 7;        // block-uniform output row-block
    const int i   = bid >> 3;

    const float c  = c_ptr[0];
    const float c2 = c * c;

    // lengthscales -> 1/l^2 (block-uniform, loop-invariant)
    float inv_l2[8];
#pragma unroll
    for (int k = 0; k < 8; ++k) {
        const float lv = l_ptr[k];
        inv_l2[k] = 1.0f / (lv * lv);
    }

    // selectors for the block-uniform runtime 'a' (no runtime reg indexing)
    float asel[8];
#pragma unroll
    for (int k = 0; k < 8; ++k) asel[k] = (k == a) ? 1.0f : 0.0f;

    // inv_l2[a] (loop-invariant selector reduction)
    float il_a = 0.0f;
#pragma unroll
    for (int k = 0; k < 8; ++k) il_a = fmaf(asel[k], inv_l2[k], il_a);

    // diagonal hits this lane's quad iff (a>>2)==h, at element (a&3)
    float dk[4];
#pragma unroll
    for (int k = 0; k < 4; ++k)
        dk[k] = (((a & 3) == k) && ((a >> 2) == h)) ? 1.0f : 0.0f;

    // X1 row (32B block-uniform broadcast, loop-invariant)
    const float4 x1a = ((const float4*)(X1 + (size_t)i * 8))[0];
    const float4 x1b = ((const float4*)(X1 + (size_t)i * 8))[1];
    const float x1v[8] = { x1a.x, x1a.y, x1a.z, x1a.w,
                           x1b.x, x1b.y, x1b.z, x1b.w };

    // out base: slab (i,a) starts at bid * m * 8 floats; lane t covers
    // byte offset t*16 within each 4KB step -> dense 1KiB per wave-instr,
    // block marches +4KB per iteration: 32KB pure sequential per block.
    float* op = out + (size_t)bid * (size_t)m * 8 + (size_t)t * 4;
    const float* xp = X2 + (size_t)p * 8;

    for (int s = 0; s < m; s += 128) {
        // X2 row for j = s + p (X2 = 32KB total -> cache-hot)
        const float4 x2a = ((const float4*)xp)[0];
        const float4 x2b = ((const float4*)xp)[1];
        const float x2v[8] = { x2a.x, x2a.y, x2a.z, x2a.w,
                               x2b.x, x2b.y, x2b.z, x2b.w };

        float D[8];
        float r2 = 0.0f;
#pragma unroll
        for (int k = 0; k < 8; ++k) {
            const float dx = x1v[k] - x2v[k];
            D[k] = dx * inv_l2[k];
            r2 += dx * D[k];                 // dx^2 * inv_l2
        }

        const float r  = sqrtf(r2);
        const float fr = (5.0f / 3.0f) * expf(-SQRT5F * r);
        const float A  = fr * (1.0f + SQRT5F * r);

        const float Acil = A * c2 * il_a;    // diagonal term value
        const float cf   = -5.0f * fr * c2;  // pair coefficient

        // D[a] via selector reduction (a block-uniform; no runtime index)
        float Da = 0.0f;
#pragma unroll
        for (int k = 0; k < 8; ++k) Da = fmaf(asel[k], D[k], Da);
        const float Dca = cf * Da;

        // this lane's 4 b-values: b = b0..b0+3, b0 = h*4 (explicit select)
        float v[4];
#pragma unroll
        for (int k = 0; k < 4; ++k) {
            const float Db = h ? D[4 + k] : D[k];
            v[k] = fmaf(dk[k], Acil, Dca * Db);
        }

        *(float4*)op = make_float4(v[0], v[1], v[2], v[3]);

        op += 128 * 8;                       // +4KB: sequential march
        xp += 128 * 8;
    }
}

extern "C" void kernel_launch(void* const* d_in, const int* in_sizes, int n_in,
                              void* d_out, int out_size, void* d_ws, size_t ws_size,
                              hipStream_t stream) {
    const float* X1 = (const float*)d_in[0];
    const float* X2 = (const float*)d_in[1];
    const float* c  = (const float*)d_in[2];
    const float* l  = (const float*)d_in[3];
    float* out = (float*)d_out;

    const int d = in_sizes[3];        // 8
    const int n = in_sizes[0] / d;    // 1024
    const int m = in_sizes[1] / d;    // 1024

    dim3 grid(n * 8);                 // block bid <-> (i = bid>>3, a = bid&7)
    dim3 block(256);                  // one contiguous 32KB slab per block
    deriv2_matern52_kernel<<<grid, block, 0, stream>>>(X1, X2, c, l, out, m);
}